// Round 7
// baseline (123.961 us; speedup 1.0000x reference)
//
#include <hip/hip_runtime.h>
#include <math.h>

typedef _Float16 h8 __attribute__((ext_vector_type(8)));
typedef _Float16 h4 __attribute__((ext_vector_type(4)));
typedef float    f4 __attribute__((ext_vector_type(4)));

#define SAMPLES 64
#define HIDDEN  256

// d_ws layout (units: _Float16). Weights plain f16 (RNE), fragment order:
//   ws[((kg*16 + ct)*64 + ln)*8 + j] = W[kg*32 + ((ln>>4)<<3) + j][ct*16 + (ln&15)]
#define OFF_W0 0            // [2][16][64][8]  = 16384 halfs
#define OFF_W1 16384        // [8][16][64][8]  = 65536
#define OFF_W2 81920
#define OFF_W3 147456       // [8][64][8] = 4096 (W3 cols padded 4->16)

__launch_bounds__(256)
__global__ void prep_weights(const float* __restrict__ W0,
                             const float* __restrict__ W1,
                             const float* __restrict__ W2,
                             const float* __restrict__ W3,
                             _Float16* __restrict__ ws)
{
    const int ln = threadIdx.x & 63;
    const int t  = blockIdx.x * 4 + (threadIdx.x >> 6);   // tile id 0..295
    if (t >= 296) return;

    const float* src; int off, kg, ct, kmax, colmax, wide;
    if (t < 32)       { src=W0; off=OFF_W0; kg=t>>4;        ct=t&15;        kmax=63;  colmax=256; wide=1; }
    else if (t < 160) { int u=t-32;  src=W1; off=OFF_W1; kg=u>>4; ct=u&15; kmax=256; colmax=256; wide=1; }
    else if (t < 288) { int u=t-160; src=W2; off=OFF_W2; kg=u>>4; ct=u&15; kmax=256; colmax=256; wide=1; }
    else              { int u=t-288; src=W3; off=OFF_W3; kg=u;    ct=0;    kmax=256; colmax=4;   wide=0; }

    const int col = ct*16 + (ln & 15);
    const int k0  = kg*32 + ((ln >> 4) << 3);
    h8 vh;
#pragma unroll
    for (int j = 0; j < 8; ++j) {
        int k = k0 + j;
        float v = (k < kmax && col < colmax) ? src[k*colmax + col] : 0.0f;
        vh[j] = (_Float16)v;   // RNE
    }
    int di = wide ? ((kg*16 + ct)*64 + ln) : (kg*64 + ln);
    ((h8*)(ws + off))[di] = vh;
}

// 16-wave decomposition: wave = (cg 0..7: channels cg*32..+31, sh 0..1: one
// ray's 4 sample-tiles). acc[2][4] = 32 AGPRs -> arch ~64 + 32 <= 128 ->
// 16 waves resident = 4 waves/SIMD (2x the R3 TLP) with NO allocator coercion.
// R3 evidence: 8-wave/acc64 structure pinned at 2 waves/SIMD (occ 19%), all
// pipes ~31%. R4/R5 WARNING: bh[2] batching / index-prefetch restructures of
// the 8-wave kernel produced WRONG RESULTS (quarantined). The kg-loop body
// below is R3's proven bh[4] pattern verbatim; only st-extent (4) and the
// ct index (cg*2+cht) differ. Weight frags are read by the sh-pair of waves
// ~concurrently -> 2nd read is an L1 hit, L2 traffic ~unchanged.
template<int NKG>
__device__ __forceinline__ void dense_layer(const _Float16* __restrict__ W,
                                            const float*    __restrict__ bias,
                                            _Float16* B, int cg, int stbase, int lane,
                                            h8 (&ca)[2],
                                            const h8* __restrict__ next0,
                                            const h8* __restrict__ next1)
{
    const int q  = lane >> 4;
    const int jl = lane & 15;
    f4 acc[2][4];
#pragma unroll
    for (int cht = 0; cht < 2; ++cht)
#pragma unroll
        for (int s = 0; s < 4; ++s) acc[cht][s] = (f4){0.f, 0.f, 0.f, 0.f};

    const h8* wp = (const h8*)W;
    const h8* bp = (const h8*)B;

#pragma unroll
    for (int kg = 0; kg < NKG; ++kg) {
        h8 na[2];
        if (kg + 1 < NKG) {
#pragma unroll
            for (int cht = 0; cht < 2; ++cht)
                na[cht] = wp[((kg+1)*16 + cg*2 + cht)*64 + lane];
        } else {           // last iter: prefetch NEXT layer's kg0 fragments
            na[0] = *next0;
            na[1] = *next1;
        }
        h8 bh[4];
#pragma unroll
        for (int s = 0; s < 4; ++s)
            bh[s] = bp[(kg*8 + stbase + s)*64 + lane];   // ds_read_b128
#pragma unroll
        for (int s = 0; s < 4; ++s) {
            acc[0][s] = __builtin_amdgcn_mfma_f32_16x16x32_f16(ca[0], bh[s], acc[0][s], 0, 0, 0);
            acc[1][s] = __builtin_amdgcn_mfma_f32_16x16x32_f16(ca[1], bh[s], acc[1][s], 0, 0, 0);
        }
        ca[0] = na[0]; ca[1] = na[1];
    }

    // bias only needed now (acc was zero-init): not live across the loop.
    f4 bb0 = ((const f4*)bias)[cg*8 + q];
    f4 bb1 = ((const f4*)bias)[cg*8 + 4 + q];

    __syncthreads();   // all waves done reading before in-place overwrite

    // relu(acc+bias) + f16 round into next layer's B-frag layout.
    // ch = cg*32 + cht*16 + q*4 + r -> kg'=cg, ln' = jl + 16*(cht*2+(q>>1)),
    // j' = (q&1)*4 + r; st carries through unchanged.
#pragma unroll
    for (int cht = 0; cht < 2; ++cht) {
        f4 bb = cht ? bb1 : bb0;
        int lnp = jl + 16*(cht*2 + (q >> 1));
        int jb  = (q & 1)*4;
#pragma unroll
        for (int s = 0; s < 4; ++s) {
            h4 vh;
#pragma unroll
            for (int r = 0; r < 4; ++r)
                vh[r] = (_Float16)fmaxf(acc[cht][s][r] + bb[r], 0.0f);
            *(h4*)(B + ((cg*8 + stbase + s)*64 + lnp)*8 + jb) = vh;
        }
    }
    __syncthreads();
}

// (1024, 1): 1 block/CU min -> 16 waves = 4 waves/SIMD -> combined VGPR cap
// 128 (r4 evidence: hipcc's 2nd arg is min BLOCKS/CU).
__launch_bounds__(1024, 1)
__global__ void nerf_fused(const float* __restrict__ origins,
                           const float* __restrict__ dirs,
                           const float* __restrict__ nearp,
                           const float* __restrict__ farp,
                           const float* __restrict__ b0,
                           const float* __restrict__ b1,
                           const float* __restrict__ b2,
                           const float* __restrict__ b3,
                           const _Float16* __restrict__ ws,
                           float* __restrict__ out,
                           int nrays)
{
    extern __shared__ _Float16 sm[];
    _Float16* B = sm;                       // [kg8][st8][64ln][8] = 32768 halfs = 64 KB
    float* headv = (float*)(sm + 32768);    // [2 ray][64 samp][4] f32 = 2 KB

    const int tid  = threadIdx.x;
    const int wv   = tid >> 6;
    const int lane = tid & 63;
    const int cg     = wv >> 1;            // channel group (32 ch)
    const int stbase = (wv & 1) * 4;       // this wave's 4 sample-tiles (one ray)
    const int ray0 = blockIdx.x * 2;
    const int ray1 = ray0 + 1;
    const int ray1c = (ray1 < nrays) ? ray1 : (nrays - 1);

    // ---- weight prefetch chain: W0 kg0 issued first, hidden under PE
    const int f10 = (cg*2 + 0)*64 + lane;
    const int f11 = (cg*2 + 1)*64 + lane;
    const h8* w0p = (const h8*)(ws + OFF_W0);
    const h8* w1p = (const h8*)(ws + OFF_W1);
    const h8* w2p = (const h8*)(ws + OFF_W2);
    const h8* w3p = (const h8*)(ws + OFF_W3);
    h8 wca[2];
    wca[0] = w0p[f10];
    wca[1] = w0p[f11];

    const float near = nearp[0];
    const float far  = farp[0];
    const float step = (far - near) * (1.0f / 64.0f);

    // ---- PE: thread -> (sample sg 0..127, k-octet o 0..7). One h8 each.
    // o = (fp, sub): fp 0..3 selects the 16-feature ladder branch (same 4
    // bodies as the verified R3 kernel), sub picks vh0/vh1. Branch uniform
    // per 2 waves. Exact double-angle ladder, no ocml in the hot path.
    {
        const int o   = tid >> 7;        // 0..7
        const int fp  = o >> 1;          // ladder branch 0..3
        const int sub = o & 1;           // which h8 of the 16-feature pair
        const int sg  = tid & 127;       // sample 0..127
        const int rr = sg >> 6;
        const int p  = sg & 63;
        const int st = rr*4 + (p >> 4);
        const int jl = p & 15;
        const int kg = fp >> 1;
        const int q0 = (fp & 1)*2;

        const float mid = (near + (float)p*step) + (near + (float)(p+1)*step)*0.5f;
        const float ox = origins[ray0*3+0], oy = origins[ray0*3+1], oz = origins[ray0*3+2];
        const float dx = dirs[ray0*3+0],    dy = dirs[ray0*3+1],    dz = dirs[ray0*3+2];
        const float o1x = origins[ray1c*3+0], o1y = origins[ray1c*3+1], o1z = origins[ray1c*3+2];
        const float d1x = dirs[ray1c*3+0],    d1y = dirs[ray1c*3+1],    d1z = dirs[ray1c*3+2];
        float c3[3];
        c3[0] = (rr ? o1x : ox) + mid*(rr ? d1x : dx);
        c3[1] = (rr ? o1y : oy) + mid*(rr ? d1y : dy);
        c3[2] = (rr ? o1z : oz) + mid*(rr ? d1z : dz);

        float ls0 = sinf(c3[0]), lc0 = cosf(c3[0]);
        float ls1 = sinf(c3[1]), lc1 = cosf(c3[1]);
        float ls2 = sinf(c3[2]), lc2 = cosf(c3[2]);
#define DBL() { float t0 = 2.f*ls0*lc0; lc0 = 1.f - 2.f*ls0*ls0; ls0 = t0; \
                float t1 = 2.f*ls1*lc1; lc1 = 1.f - 2.f*ls1*ls1; ls1 = t1; \
                float t2 = 2.f*ls2*lc2; lc2 = 1.f - 2.f*ls2*ls2; ls2 = t2; }
        h8 vh0, vh1;
        if (fp == 0) {
            vh0[0]=(_Float16)c3[0]; vh0[1]=(_Float16)c3[1]; vh0[2]=(_Float16)c3[2];
            vh0[3]=(_Float16)ls0;   vh0[4]=(_Float16)ls1;   vh0[5]=(_Float16)ls2;
            vh0[6]=(_Float16)lc0;   vh0[7]=(_Float16)lc1;   vh1[0]=(_Float16)lc2;
            DBL();  // l1
            vh1[1]=(_Float16)ls0; vh1[2]=(_Float16)ls1; vh1[3]=(_Float16)ls2;
            vh1[4]=(_Float16)lc0; vh1[5]=(_Float16)lc1; vh1[6]=(_Float16)lc2;
            DBL();  // l2
            vh1[7]=(_Float16)ls0;
        } else if (fp == 1) {
            DBL(); DBL();  // l2
            vh0[0]=(_Float16)ls1; vh0[1]=(_Float16)ls2;
            vh0[2]=(_Float16)lc0; vh0[3]=(_Float16)lc1; vh0[4]=(_Float16)lc2;
            DBL();  // l3
            vh0[5]=(_Float16)ls0; vh0[6]=(_Float16)ls1; vh0[7]=(_Float16)ls2;
            vh1[0]=(_Float16)lc0; vh1[1]=(_Float16)lc1; vh1[2]=(_Float16)lc2;
            DBL();  // l4
            vh1[3]=(_Float16)ls0; vh1[4]=(_Float16)ls1; vh1[5]=(_Float16)ls2;
            vh1[6]=(_Float16)lc0; vh1[7]=(_Float16)lc1;
        } else if (fp == 2) {
            DBL(); DBL(); DBL(); DBL();  // l4
            vh0[0]=(_Float16)lc2;
            DBL();  // l5
            vh0[1]=(_Float16)ls0; vh0[2]=(_Float16)ls1; vh0[3]=(_Float16)ls2;
            vh0[4]=(_Float16)lc0; vh0[5]=(_Float16)lc1; vh0[6]=(_Float16)lc2;
            DBL();  // l6
            vh0[7]=(_Float16)ls0; vh1[0]=(_Float16)ls1; vh1[1]=(_Float16)ls2;
            vh1[2]=(_Float16)lc0; vh1[3]=(_Float16)lc1; vh1[4]=(_Float16)lc2;
            DBL();  // l7
            vh1[5]=(_Float16)ls0; vh1[6]=(_Float16)ls1; vh1[7]=(_Float16)ls2;
        } else {
            DBL(); DBL(); DBL(); DBL(); DBL(); DBL(); DBL();  // l7
            vh0[0]=(_Float16)lc0; vh0[1]=(_Float16)lc1; vh0[2]=(_Float16)lc2;
            DBL();  // l8
            vh0[3]=(_Float16)ls0; vh0[4]=(_Float16)ls1; vh0[5]=(_Float16)ls2;
            vh0[6]=(_Float16)lc0; vh0[7]=(_Float16)lc1; vh1[0]=(_Float16)lc2;
            DBL();  // l9
            vh1[1]=(_Float16)ls0; vh1[2]=(_Float16)ls1; vh1[3]=(_Float16)ls2;
            vh1[4]=(_Float16)lc0; vh1[5]=(_Float16)lc1; vh1[6]=(_Float16)lc2;
            vh1[7]=(_Float16)0.0f;
        }
#undef DBL
        ((h8*)B)[(kg*8 + st)*64 + (q0 + sub)*16 + jl] = sub ? vh1 : vh0;
    }
    __syncthreads();

    dense_layer<2>(ws+OFF_W0, b0, B, cg, stbase, lane, wca, &w1p[f10], &w1p[f11]);
    dense_layer<8>(ws+OFF_W1, b1, B, cg, stbase, lane, wca, &w2p[f10], &w2p[f11]);
    dense_layer<8>(ws+OFF_W2, b2, B, cg, stbase, lane, wca,
                   &w3p[cg*64 + lane], &w3p[cg*64 + lane]);

    // ---- head: D[16pad ch][128 samp], K split: wave (cg, sh) does kg=cg,
    // its own 4 sample-tiles.
    f4 hacc[4];
    {
        h8 ah = wca[0];                     // W3 frag via the prefetch chain
        const h8* bp = (const h8*)B;
#pragma unroll
        for (int s = 0; s < 4; ++s) {
            f4 z = (f4){0.f, 0.f, 0.f, 0.f};
            hacc[s] = __builtin_amdgcn_mfma_f32_16x16x32_f16(ah, bp[(cg*8 + stbase + s)*64 + lane], z, 0, 0, 0);
        }
    }
    __syncthreads();                       // B reads done -> safe to alias

    f4* part = (f4*)sm;                    // [cg8][st8][lane] f4 = 64 KB (B region)
#pragma unroll
    for (int s = 0; s < 4; ++s) part[(cg*8 + stbase + s)*64 + lane] = hacc[s];
    __syncthreads();

    if (tid < 512) {
        int stt = tid >> 6, l = tid & 63;
        f4 s = part[(0*8 + stt)*64 + l];
#pragma unroll
        for (int w = 1; w < 8; ++w) s += part[(w*8 + stt)*64 + l];
        int q = l >> 4, jl = l & 15;
        if (q == 0) {                      // rows 0..3 = the real 4 channels
            s += *(const f4*)b3;
            ((f4*)headv)[(stt >> 2)*64 + (stt & 3)*16 + jl] = s;  // [ray][sample]
        }
    }
    __syncthreads();

    // ---- compositing: waves 0-1, lane = sample, wave = ray
    if (tid < 128) {
        const int rr = tid >> 6;
        const int p  = tid & 63;
        f4 f = ((const f4*)headv)[rr*64 + p];
        float sigma = fmaxf(f[3], 0.0f);
        float delta = (near + (float)(p + 1)*step) - (near + (float)p*step);
        float alpha = 1.0f - expf(-sigma * delta);
        float om    = 1.0f - alpha;

        float prod = om;
#pragma unroll
        for (int off = 1; off < 64; off <<= 1) {
            float v = __shfl_up(prod, off, 64);
            if (p >= off) prod *= v;
        }
        float T = __shfl_up(prod, 1, 64);
        if (p == 0) T = 1.0f;
        float w = T * alpha;

        float r  = w * (1.0f / (1.0f + expf(-f[0])));
        float g  = w * (1.0f / (1.0f + expf(-f[1])));
        float bb = w * (1.0f / (1.0f + expf(-f[2])));
#pragma unroll
        for (int off = 32; off > 0; off >>= 1) {
            r  += __shfl_down(r,  off, 64);
            g  += __shfl_down(g,  off, 64);
            bb += __shfl_down(bb, off, 64);
        }
        if (p == 0 && ray0 + rr < nrays) {
            out[(ray0 + rr)*3 + 0] = r;
            out[(ray0 + rr)*3 + 1] = g;
            out[(ray0 + rr)*3 + 2] = bb;
        }
    }
}

extern "C" void kernel_launch(void* const* d_in, const int* in_sizes, int n_in,
                              void* d_out, int out_size, void* d_ws, size_t ws_size,
                              hipStream_t stream) {
    const float* origins = (const float*)d_in[0];
    const float* dirs    = (const float*)d_in[1];
    const float* nearp   = (const float*)d_in[2];
    const float* farp    = (const float*)d_in[3];
    const float* W0      = (const float*)d_in[4];
    const float* b0      = (const float*)d_in[5];
    const float* W1      = (const float*)d_in[6];
    const float* b1      = (const float*)d_in[7];
    const float* W2      = (const float*)d_in[8];
    const float* b2      = (const float*)d_in[9];
    const float* W3      = (const float*)d_in[10];
    const float* b3      = (const float*)d_in[11];
    float* out           = (float*)d_out;
    _Float16* ws         = (_Float16*)d_ws;

    const int nrays = in_sizes[0] / 3;
    const int nblk  = (nrays + 1) / 2;

    prep_weights<<<dim3(74), dim3(256), 0, stream>>>(W0, W1, W2, W3, ws);

    const size_t shmem = 32768 * sizeof(_Float16) + 128 * sizeof(f4);   // 66 KiB
    hipFuncSetAttribute(reinterpret_cast<const void*>(nerf_fused),
                        hipFuncAttributeMaxDynamicSharedMemorySize,
                        (int)shmem);
    nerf_fused<<<dim3(nblk), dim3(1024), shmem, stream>>>(
        origins, dirs, nearp, farp, b0, b1, b2, b3, ws, out, nrays);
}

// Round 11
// 120.703 us; speedup vs baseline: 1.0270x; 1.0270x over previous
//
#include <hip/hip_runtime.h>
#include <math.h>

typedef _Float16 h8 __attribute__((ext_vector_type(8)));
typedef _Float16 h4 __attribute__((ext_vector_type(4)));
typedef float    f4 __attribute__((ext_vector_type(4)));

#define SAMPLES 64
#define HIDDEN  256

// d_ws layout (units: _Float16). Weights plain f16 (RNE), fragment order:
//   ws[((kg*16 + ct)*64 + ln)*8 + j] = W[kg*32 + ((ln>>4)<<3) + j][ct*16 + (ln&15)]
#define OFF_W0 0            // [2][16][64][8]  = 16384 halfs
#define OFF_W1 16384        // [8][16][64][8]  = 65536
#define OFF_W2 81920
#define OFF_W3 147456       // [8][64][8] = 4096 (W3 cols padded 4->16)

__launch_bounds__(256)
__global__ void prep_weights(const float* __restrict__ W0,
                             const float* __restrict__ W1,
                             const float* __restrict__ W2,
                             const float* __restrict__ W3,
                             _Float16* __restrict__ ws)
{
    const int ln = threadIdx.x & 63;
    const int t  = blockIdx.x * 4 + (threadIdx.x >> 6);   // tile id 0..295
    if (t >= 296) return;

    const float* src; int off, kg, ct, kmax, colmax, wide;
    if (t < 32)       { src=W0; off=OFF_W0; kg=t>>4;        ct=t&15;        kmax=63;  colmax=256; wide=1; }
    else if (t < 160) { int u=t-32;  src=W1; off=OFF_W1; kg=u>>4; ct=u&15; kmax=256; colmax=256; wide=1; }
    else if (t < 288) { int u=t-160; src=W2; off=OFF_W2; kg=u>>4; ct=u&15; kmax=256; colmax=256; wide=1; }
    else              { int u=t-288; src=W3; off=OFF_W3; kg=u;    ct=0;    kmax=256; colmax=4;   wide=0; }

    const int col = ct*16 + (ln & 15);
    const int k0  = kg*32 + ((ln >> 4) << 3);
    h8 vh;
#pragma unroll
    for (int j = 0; j < 8; ++j) {
        int k = k0 + j;
        float v = (k < kmax && col < colmax) ? src[k*colmax + col] : 0.0f;
        vh[j] = (_Float16)v;   // RNE
    }
    int di = wide ? ((kg*16 + ct)*64 + ln) : (kg*64 + ln);
    ((h8*)(ws + off))[di] = vh;
}

// Swapped orientation, TWO rays per block. Wave wv owns channels wv*32..+31
// x 128 samples. acc[2][8] = 64 AGPRs (unified file) -> arch VGPR must reach
// <= 64 NATURALLY so arch+acc <= 128 -> 2 blocks/CU resident.
// R11 EXPERIMENT: the cross-layer wca/next prefetch chain (R3 addition) held
// ~8 VGPRs live across the whole kernel. DELETED; dense_layer self-loads its
// kg0 fragments at entry and uses R2's kn-clamp last-iter reload -- both
// copied VERBATIM from the R2 kernel (harness-PASSED at 73.7us). All other
// text is byte-identical to R6 (PASSED, 49.5us, absmax 6.103516e-05).
// CURSE LOG (R4/R5/R8/R9/R10 wrong results, incl. a scheduling-only pragma):
// failures are NOT source-semantic; suspect regalloc-dependent miscompile.
// Only proven text blocks are composed here; if this fails, revert to R6
// permanently.
template<int NKG>
__device__ __forceinline__ void dense_layer(const _Float16* __restrict__ W,
                                            const float*    __restrict__ bias,
                                            _Float16* B, int wv, int lane)
{
    const int q  = lane >> 4;
    const int jl = lane & 15;
    f4 acc[2][8];
#pragma unroll
    for (int cht = 0; cht < 2; ++cht)
#pragma unroll
        for (int st = 0; st < 8; ++st) acc[cht][st] = (f4){0.f, 0.f, 0.f, 0.f};

    const h8* wp = (const h8*)W;
    const h8* bp = (const h8*)B;

    h8 ca[2];
#pragma unroll
    for (int cht = 0; cht < 2; ++cht)              // kg=0 entry load (R2 text)
        ca[cht] = wp[(wv*2 + cht)*64 + lane];

#pragma unroll
    for (int kg = 0; kg < NKG; ++kg) {
        h8 na[2];
        int kn = (kg + 1 < NKG) ? kg + 1 : kg;     // harmless re-load on last iter
#pragma unroll
        for (int cht = 0; cht < 2; ++cht)
            na[cht] = wp[(kn*16 + wv*2 + cht)*64 + lane];
#pragma unroll
        for (int sh = 0; sh < 2; ++sh) {
            h8 bh[4];
#pragma unroll
            for (int s = 0; s < 4; ++s)
                bh[s] = bp[(kg*8 + sh*4 + s)*64 + lane];   // ds_read_b128
#pragma unroll
            for (int s = 0; s < 4; ++s) {
                acc[0][sh*4+s] = __builtin_amdgcn_mfma_f32_16x16x32_f16(ca[0], bh[s], acc[0][sh*4+s], 0, 0, 0);
                acc[1][sh*4+s] = __builtin_amdgcn_mfma_f32_16x16x32_f16(ca[1], bh[s], acc[1][sh*4+s], 0, 0, 0);
            }
        }
        ca[0] = na[0]; ca[1] = na[1];
    }

    // bias only needed now (acc was zero-init): not live across the loop.
    f4 bb0 = ((const f4*)bias)[wv*8 + q];
    f4 bb1 = ((const f4*)bias)[wv*8 + 4 + q];

    __syncthreads();   // all waves done reading before in-place overwrite

    // relu(acc+bias) + f16 round into next layer's B-frag layout.
#pragma unroll
    for (int cht = 0; cht < 2; ++cht) {
        f4 bb = cht ? bb1 : bb0;
        int lnp = jl + 16*(cht*2 + (q >> 1));
        int jb  = (q & 1)*4;
#pragma unroll
        for (int st = 0; st < 8; ++st) {
            h4 vh;
#pragma unroll
            for (int r = 0; r < 4; ++r)
                vh[r] = (_Float16)fmaxf(acc[cht][st][r] + bb[r], 0.0f);
            *(h4*)(B + ((wv*8 + st)*64 + lnp)*8 + jb) = vh;
        }
    }
    __syncthreads();
}

__launch_bounds__(512, 2)
__global__ void nerf_fused(const float* __restrict__ origins,
                           const float* __restrict__ dirs,
                           const float* __restrict__ nearp,
                           const float* __restrict__ farp,
                           const float* __restrict__ b0,
                           const float* __restrict__ b1,
                           const float* __restrict__ b2,
                           const float* __restrict__ b3,
                           const _Float16* __restrict__ ws,
                           float* __restrict__ out,
                           int nrays)
{
    extern __shared__ _Float16 sm[];
    _Float16* B = sm;                       // [kg4][st8][64ln][8] = 32768 halfs = 64 KB
    float* headv = (float*)(sm + 32768);    // [2 ray][64 samp][4] f32 = 2 KB

    const int tid  = threadIdx.x;
    const int wv   = tid >> 6;
    const int lane = tid & 63;
    const int ray0 = blockIdx.x * 2;
    const int ray1 = ray0 + 1;
    const int ray1c = (ray1 < nrays) ? ray1 : (nrays - 1);

    const float near = nearp[0];
    const float far  = farp[0];
    const float step = (far - near) * (1.0f / 64.0f);

    // ---- PE: thread -> (sample sg, 16-feature chunk f). f is wave-uniform.
    // Exact double-angle ladder from accurate base sincos (args |x|<~15);
    // ladder error <= ~5e-5 << f16 rounding. No ocml calls in the hot path.
    {
        const int f  = tid >> 7;          // chunk 0..3 (uniform per wave pair)
        const int sg = tid & 127;         // sample 0..127
        const int rr = sg >> 6;
        const int p  = sg & 63;
        const int st = rr*4 + (p >> 4);
        const int jl = p & 15;
        const int kg = f >> 1;
        const int q0 = (f & 1)*2;

        const float mid = (near + (float)p*step) + (near + (float)(p+1)*step)*0.5f;
        const float ox = origins[ray0*3+0], oy = origins[ray0*3+1], oz = origins[ray0*3+2];
        const float dx = dirs[ray0*3+0],    dy = dirs[ray0*3+1],    dz = dirs[ray0*3+2];
        const float o1x = origins[ray1c*3+0], o1y = origins[ray1c*3+1], o1z = origins[ray1c*3+2];
        const float d1x = dirs[ray1c*3+0],    d1y = dirs[ray1c*3+1],    d1z = dirs[ray1c*3+2];
        float c3[3];
        c3[0] = (rr ? o1x : ox) + mid*(rr ? d1x : dx);
        c3[1] = (rr ? o1y : oy) + mid*(rr ? d1y : dy);
        c3[2] = (rr ? o1z : oz) + mid*(rr ? d1z : dz);

        float ls0 = sinf(c3[0]), lc0 = cosf(c3[0]);
        float ls1 = sinf(c3[1]), lc1 = cosf(c3[1]);
        float ls2 = sinf(c3[2]), lc2 = cosf(c3[2]);
#define DBL() { float t0 = 2.f*ls0*lc0; lc0 = 1.f - 2.f*ls0*ls0; ls0 = t0; \
                float t1 = 2.f*ls1*lc1; lc1 = 1.f - 2.f*ls1*ls1; ls1 = t1; \
                float t2 = 2.f*ls2*lc2; lc2 = 1.f - 2.f*ls2*ls2; ls2 = t2; }
        h8 vh0, vh1;
        if (f == 0) {
            vh0[0]=(_Float16)c3[0]; vh0[1]=(_Float16)c3[1]; vh0[2]=(_Float16)c3[2];
            vh0[3]=(_Float16)ls0;   vh0[4]=(_Float16)ls1;   vh0[5]=(_Float16)ls2;
            vh0[6]=(_Float16)lc0;   vh0[7]=(_Float16)lc1;   vh1[0]=(_Float16)lc2;
            DBL();  // l1
            vh1[1]=(_Float16)ls0; vh1[2]=(_Float16)ls1; vh1[3]=(_Float16)ls2;
            vh1[4]=(_Float16)lc0; vh1[5]=(_Float16)lc1; vh1[6]=(_Float16)lc2;
            DBL();  // l2
            vh1[7]=(_Float16)ls0;
        } else if (f == 1) {
            DBL(); DBL();  // l2
            vh0[0]=(_Float16)ls1; vh0[1]=(_Float16)ls2;
            vh0[2]=(_Float16)lc0; vh0[3]=(_Float16)lc1; vh0[4]=(_Float16)lc2;
            DBL();  // l3
            vh0[5]=(_Float16)ls0; vh0[6]=(_Float16)ls1; vh0[7]=(_Float16)ls2;
            vh1[0]=(_Float16)lc0; vh1[1]=(_Float16)lc1; vh1[2]=(_Float16)lc2;
            DBL();  // l4
            vh1[3]=(_Float16)ls0; vh1[4]=(_Float16)ls1; vh1[5]=(_Float16)ls2;
            vh1[6]=(_Float16)lc0; vh1[7]=(_Float16)lc1;
        } else if (f == 2) {
            DBL(); DBL(); DBL(); DBL();  // l4
            vh0[0]=(_Float16)lc2;
            DBL();  // l5
            vh0[1]=(_Float16)ls0; vh0[2]=(_Float16)ls1; vh0[3]=(_Float16)ls2;
            vh0[4]=(_Float16)lc0; vh0[5]=(_Float16)lc1; vh0[6]=(_Float16)lc2;
            DBL();  // l6
            vh0[7]=(_Float16)ls0; vh1[0]=(_Float16)ls1; vh1[1]=(_Float16)ls2;
            vh1[2]=(_Float16)lc0; vh1[3]=(_Float16)lc1; vh1[4]=(_Float16)lc2;
            DBL();  // l7
            vh1[5]=(_Float16)ls0; vh1[6]=(_Float16)ls1; vh1[7]=(_Float16)ls2;
        } else {
            DBL(); DBL(); DBL(); DBL(); DBL(); DBL(); DBL();  // l7
            vh0[0]=(_Float16)lc0; vh0[1]=(_Float16)lc1; vh0[2]=(_Float16)lc2;
            DBL();  // l8
            vh0[3]=(_Float16)ls0; vh0[4]=(_Float16)ls1; vh0[5]=(_Float16)ls2;
            vh0[6]=(_Float16)lc0; vh0[7]=(_Float16)lc1; vh1[0]=(_Float16)lc2;
            DBL();  // l9
            vh1[1]=(_Float16)ls0; vh1[2]=(_Float16)ls1; vh1[3]=(_Float16)ls2;
            vh1[4]=(_Float16)lc0; vh1[5]=(_Float16)lc1; vh1[6]=(_Float16)lc2;
            vh1[7]=(_Float16)0.0f;
        }
#undef DBL
        ((h8*)B)[(kg*8 + st)*64 + (q0    )*16 + jl] = vh0;
        ((h8*)B)[(kg*8 + st)*64 + (q0 + 1)*16 + jl] = vh1;
    }
    __syncthreads();

    dense_layer<2>(ws+OFF_W0, b0, B, wv, lane);
    dense_layer<8>(ws+OFF_W1, b1, B, wv, lane);
    dense_layer<8>(ws+OFF_W2, b2, B, wv, lane);

    // ---- head: D[16pad ch][128 samp], K split across 8 waves (kg = wv)
    f4 hacc[8];
    {
        h8 ah = ((const h8*)(ws+OFF_W3))[wv*64 + lane];   // R2 text
        const h8* bp = (const h8*)B;
#pragma unroll
        for (int st = 0; st < 8; ++st) {
            f4 z = (f4){0.f, 0.f, 0.f, 0.f};
            hacc[st] = __builtin_amdgcn_mfma_f32_16x16x32_f16(ah, bp[(wv*8 + st)*64 + lane], z, 0, 0, 0);
        }
    }
    __syncthreads();                       // B reads done -> safe to alias

    f4* part = (f4*)sm;                    // [wv][st8][lane] f4 = 64 KB (B region)
#pragma unroll
    for (int st = 0; st < 8; ++st) part[(wv*8 + st)*64 + lane] = hacc[st];
    __syncthreads();

    {
        int stt = tid >> 6, l = tid & 63;
        f4 s = part[(0*8 + stt)*64 + l];
#pragma unroll
        for (int w = 1; w < 8; ++w) s += part[(w*8 + stt)*64 + l];
        int q = l >> 4, jl = l & 15;
        if (q == 0) {                      // rows 0..3 = the real 4 channels
            s += *(const f4*)b3;
            ((f4*)headv)[(stt >> 2)*64 + (stt & 3)*16 + jl] = s;  // [ray][sample]
        }
    }
    __syncthreads();

    // ---- compositing: waves 0-1, lane = sample, wave = ray
    if (tid < 128) {
        const int rr = tid >> 6;
        const int p  = tid & 63;
        f4 f = ((const f4*)headv)[rr*64 + p];
        float sigma = fmaxf(f[3], 0.0f);
        float delta = (near + (float)(p + 1)*step) - (near + (float)p*step);
        float alpha = 1.0f - expf(-sigma * delta);
        float om    = 1.0f - alpha;

        float prod = om;
#pragma unroll
        for (int off = 1; off < 64; off <<= 1) {
            float v = __shfl_up(prod, off, 64);
            if (p >= off) prod *= v;
        }
        float T = __shfl_up(prod, 1, 64);
        if (p == 0) T = 1.0f;
        float w = T * alpha;

        float r  = w * (1.0f / (1.0f + expf(-f[0])));
        float g  = w * (1.0f / (1.0f + expf(-f[1])));
        float bb = w * (1.0f / (1.0f + expf(-f[2])));
#pragma unroll
        for (int off = 32; off > 0; off >>= 1) {
            r  += __shfl_down(r,  off, 64);
            g  += __shfl_down(g,  off, 64);
            bb += __shfl_down(bb, off, 64);
        }
        if (p == 0 && ray0 + rr < nrays) {
            out[(ray0 + rr)*3 + 0] = r;
            out[(ray0 + rr)*3 + 1] = g;
            out[(ray0 + rr)*3 + 2] = bb;
        }
    }
}

extern "C" void kernel_launch(void* const* d_in, const int* in_sizes, int n_in,
                              void* d_out, int out_size, void* d_ws, size_t ws_size,
                              hipStream_t stream) {
    const float* origins = (const float*)d_in[0];
    const float* dirs    = (const float*)d_in[1];
    const float* nearp   = (const float*)d_in[2];
    const float* farp    = (const float*)d_in[3];
    const float* W0      = (const float*)d_in[4];
    const float* b0      = (const float*)d_in[5];
    const float* W1      = (const float*)d_in[6];
    const float* b1      = (const float*)d_in[7];
    const float* W2      = (const float*)d_in[8];
    const float* b2      = (const float*)d_in[9];
    const float* W3      = (const float*)d_in[10];
    const float* b3      = (const float*)d_in[11];
    float* out           = (float*)d_out;
    _Float16* ws         = (_Float16*)d_ws;

    const int nrays = in_sizes[0] / 3;
    const int nblk  = (nrays + 1) / 2;

    prep_weights<<<dim3(74), dim3(256), 0, stream>>>(W0, W1, W2, W3, ws);

    const size_t shmem = 32768 * sizeof(_Float16) + 128 * sizeof(f4);   // 66 KiB
    hipFuncSetAttribute(reinterpret_cast<const void*>(nerf_fused),
                        hipFuncAttributeMaxDynamicSharedMemorySize,
                        (int)shmem);
    nerf_fused<<<dim3(nblk), dim3(512), shmem, stream>>>(
        origins, dirs, nearp, farp, b0, b1, b2, b3, ws, out, nrays);
}

// Round 12
// 117.488 us; speedup vs baseline: 1.0551x; 1.0274x over previous
//
#include <hip/hip_runtime.h>
#include <math.h>

typedef _Float16 h8 __attribute__((ext_vector_type(8)));
typedef _Float16 h4 __attribute__((ext_vector_type(4)));
typedef float    f4 __attribute__((ext_vector_type(4)));

#define SAMPLES 64
#define HIDDEN  256

// d_ws layout (units: _Float16). Weights plain f16 (RNE), fragment order:
//   ws[((kg*16 + ct)*64 + ln)*8 + j] = W[kg*32 + ((ln>>4)<<3) + j][ct*16 + (ln&15)]
#define OFF_W0 0            // [2][16][64][8]  = 16384 halfs
#define OFF_W1 16384        // [8][16][64][8]  = 65536
#define OFF_W2 81920
#define OFF_W3 147456       // [8][64][8] = 4096 (W3 cols padded 4->16)

__launch_bounds__(256)
__global__ void prep_weights(const float* __restrict__ W0,
                             const float* __restrict__ W1,
                             const float* __restrict__ W2,
                             const float* __restrict__ W3,
                             _Float16* __restrict__ ws)
{
    const int ln = threadIdx.x & 63;
    const int t  = blockIdx.x * 4 + (threadIdx.x >> 6);   // tile id 0..295
    if (t >= 296) return;

    const float* src; int off, kg, ct, kmax, colmax, wide;
    if (t < 32)       { src=W0; off=OFF_W0; kg=t>>4;        ct=t&15;        kmax=63;  colmax=256; wide=1; }
    else if (t < 160) { int u=t-32;  src=W1; off=OFF_W1; kg=u>>4; ct=u&15; kmax=256; colmax=256; wide=1; }
    else if (t < 288) { int u=t-160; src=W2; off=OFF_W2; kg=u>>4; ct=u&15; kmax=256; colmax=256; wide=1; }
    else              { int u=t-288; src=W3; off=OFF_W3; kg=u;    ct=0;    kmax=256; colmax=4;   wide=0; }

    const int col = ct*16 + (ln & 15);
    const int k0  = kg*32 + ((ln >> 4) << 3);
    h8 vh;
#pragma unroll
    for (int j = 0; j < 8; ++j) {
        int k = k0 + j;
        float v = (k < kmax && col < colmax) ? src[k*colmax + col] : 0.0f;
        vh[j] = (_Float16)v;   // RNE
    }
    int di = wide ? ((kg*16 + ct)*64 + ln) : (kg*64 + ln);
    ((h8*)(ws + off))[di] = vh;
}

// FINAL SESSION ANCHOR (byte-exact R3/R6 code; best verified: fused 49.5us,
// total 118.7us, absmax 6.103516e-05).
// Swapped orientation, TWO rays per block. Wave wv owns channels wv*32..+31
// x 128 samples. acc[2][8] = 64 AGPRs (unified file); arch VGPR 72 ->
// combined 136 > 128 -> 3 waves/SIMD -> 1 block/CU (occ ~20%).
// EXPERIMENT LEDGER past this point (do not retry):
//  R4 waves_per_eu(4) cap ......... WRONG RESULTS (forced-cap spills)
//  R5 index-prefetch slimming ..... WRONG RESULTS
//  R7 16-wave acc[2][4] ........... correct, occ 40%, but SLOWER (56us):
//     extra lockstep waves in one barrier domain don't overlap phases and
//     double weight L2 traffic. Occupancy was never the binding constraint.
//  R8 ping-pong LDS (1 barrier/layer) WRONG RESULTS
//  R9 1-ray/block + split ladder .. WRONG RESULTS
//  R10 #pragma unroll 1 ONLY ...... WRONG RESULTS -- scheduling-only change;
//     proves failures are NOT source-semantic (suspect regalloc/AGPR-copy
//     miscompile knife-edge). Any codegen perturbation is high-risk.
//  R11 prefetch-chain deletion .... correct, arch only 72->68 (still >64),
//     SLOWER (59.5us, layer-entry stall).
// Ceiling statement: NOT a hardware roofline (MfmaUtil 32%, VALUBusy 31%,
// HBM 0.4%; MFMA floor ~19us vs 49.5us measured). Binding constraint is the
// 1-block/CU phase-serialized barrier chain; all relaxation levers are
// tested-negative or blocked by the miscompile knife-edge.
template<int NKG>
__device__ __forceinline__ void dense_layer(const _Float16* __restrict__ W,
                                            const float*    __restrict__ bias,
                                            _Float16* B, int wv, int lane,
                                            h8 (&ca)[2],
                                            const h8* __restrict__ next0,
                                            const h8* __restrict__ next1)
{
    const int q  = lane >> 4;
    const int jl = lane & 15;
    f4 acc[2][8];
#pragma unroll
    for (int cht = 0; cht < 2; ++cht)
#pragma unroll
        for (int st = 0; st < 8; ++st) acc[cht][st] = (f4){0.f, 0.f, 0.f, 0.f};

    const h8* wp = (const h8*)W;
    const h8* bp = (const h8*)B;

#pragma unroll
    for (int kg = 0; kg < NKG; ++kg) {
        h8 na[2];
        if (kg + 1 < NKG) {
#pragma unroll
            for (int cht = 0; cht < 2; ++cht)
                na[cht] = wp[((kg+1)*16 + wv*2 + cht)*64 + lane];
        } else {           // last iter: prefetch NEXT layer's kg0 fragments
            na[0] = *next0;
            na[1] = *next1;
        }
#pragma unroll
        for (int sh = 0; sh < 2; ++sh) {
            h8 bh[4];
#pragma unroll
            for (int s = 0; s < 4; ++s)
                bh[s] = bp[(kg*8 + sh*4 + s)*64 + lane];   // ds_read_b128
#pragma unroll
            for (int s = 0; s < 4; ++s) {
                acc[0][sh*4+s] = __builtin_amdgcn_mfma_f32_16x16x32_f16(ca[0], bh[s], acc[0][sh*4+s], 0, 0, 0);
                acc[1][sh*4+s] = __builtin_amdgcn_mfma_f32_16x16x32_f16(ca[1], bh[s], acc[1][sh*4+s], 0, 0, 0);
            }
        }
        ca[0] = na[0]; ca[1] = na[1];
    }

    // bias only needed now (acc was zero-init): not live across the loop.
    f4 bb0 = ((const f4*)bias)[wv*8 + q];
    f4 bb1 = ((const f4*)bias)[wv*8 + 4 + q];

    __syncthreads();   // all waves done reading before in-place overwrite

    // relu(acc+bias) + f16 round into next layer's B-frag layout.
#pragma unroll
    for (int cht = 0; cht < 2; ++cht) {
        f4 bb = cht ? bb1 : bb0;
        int lnp = jl + 16*(cht*2 + (q >> 1));
        int jb  = (q & 1)*4;
#pragma unroll
        for (int st = 0; st < 8; ++st) {
            h4 vh;
#pragma unroll
            for (int r = 0; r < 4; ++r)
                vh[r] = (_Float16)fmaxf(acc[cht][st][r] + bb[r], 0.0f);
            *(h4*)(B + ((wv*8 + st)*64 + lnp)*8 + jb) = vh;
        }
    }
    __syncthreads();
}

__launch_bounds__(512, 2)
__global__ void nerf_fused(const float* __restrict__ origins,
                           const float* __restrict__ dirs,
                           const float* __restrict__ nearp,
                           const float* __restrict__ farp,
                           const float* __restrict__ b0,
                           const float* __restrict__ b1,
                           const float* __restrict__ b2,
                           const float* __restrict__ b3,
                           const _Float16* __restrict__ ws,
                           float* __restrict__ out,
                           int nrays)
{
    extern __shared__ _Float16 sm[];
    _Float16* B = sm;                       // [kg4][st8][64ln][8] = 32768 halfs = 64 KB
    float* headv = (float*)(sm + 32768);    // [2 ray][64 samp][4] f32 = 2 KB

    const int tid  = threadIdx.x;
    const int wv   = tid >> 6;
    const int lane = tid & 63;
    const int ray0 = blockIdx.x * 2;
    const int ray1 = ray0 + 1;
    const int ray1c = (ray1 < nrays) ? ray1 : (nrays - 1);

    // ---- weight prefetch chain: W0 kg0 issued first, hidden under PE
    const int fi0 = (wv*2 + 0)*64 + lane;
    const int fi1 = (wv*2 + 1)*64 + lane;
    const h8* w0p = (const h8*)(ws + OFF_W0);
    const h8* w1p = (const h8*)(ws + OFF_W1);
    const h8* w2p = (const h8*)(ws + OFF_W2);
    const h8* w3p = (const h8*)(ws + OFF_W3);
    h8 wca[2];
    wca[0] = w0p[fi0];
    wca[1] = w0p[fi1];

    const float near = nearp[0];
    const float far  = farp[0];
    const float step = (far - near) * (1.0f / 64.0f);

    // ---- PE: thread -> (sample sg, 16-feature chunk f). f is wave-uniform.
    // Exact double-angle ladder from accurate base sincos (args |x|<~15);
    // ladder error <= ~5e-5 << f16 rounding. No ocml calls in the hot path.
    {
        const int f  = tid >> 7;          // chunk 0..3 (uniform per wave pair)
        const int sg = tid & 127;         // sample 0..127
        const int rr = sg >> 6;
        const int p  = sg & 63;
        const int st = rr*4 + (p >> 4);
        const int jl = p & 15;
        const int kg = f >> 1;
        const int q0 = (f & 1)*2;

        const float mid = (near + (float)p*step) + (near + (float)(p+1)*step)*0.5f;
        const float ox = origins[ray0*3+0], oy = origins[ray0*3+1], oz = origins[ray0*3+2];
        const float dx = dirs[ray0*3+0],    dy = dirs[ray0*3+1],    dz = dirs[ray0*3+2];
        const float o1x = origins[ray1c*3+0], o1y = origins[ray1c*3+1], o1z = origins[ray1c*3+2];
        const float d1x = dirs[ray1c*3+0],    d1y = dirs[ray1c*3+1],    d1z = dirs[ray1c*3+2];
        float c3[3];
        c3[0] = (rr ? o1x : ox) + mid*(rr ? d1x : dx);
        c3[1] = (rr ? o1y : oy) + mid*(rr ? d1y : dy);
        c3[2] = (rr ? o1z : oz) + mid*(rr ? d1z : dz);

        float ls0 = sinf(c3[0]), lc0 = cosf(c3[0]);
        float ls1 = sinf(c3[1]), lc1 = cosf(c3[1]);
        float ls2 = sinf(c3[2]), lc2 = cosf(c3[2]);
#define DBL() { float t0 = 2.f*ls0*lc0; lc0 = 1.f - 2.f*ls0*ls0; ls0 = t0; \
                float t1 = 2.f*ls1*lc1; lc1 = 1.f - 2.f*ls1*ls1; ls1 = t1; \
                float t2 = 2.f*ls2*lc2; lc2 = 1.f - 2.f*ls2*ls2; ls2 = t2; }
        h8 vh0, vh1;
        if (f == 0) {
            vh0[0]=(_Float16)c3[0]; vh0[1]=(_Float16)c3[1]; vh0[2]=(_Float16)c3[2];
            vh0[3]=(_Float16)ls0;   vh0[4]=(_Float16)ls1;   vh0[5]=(_Float16)ls2;
            vh0[6]=(_Float16)lc0;   vh0[7]=(_Float16)lc1;   vh1[0]=(_Float16)lc2;
            DBL();  // l1
            vh1[1]=(_Float16)ls0; vh1[2]=(_Float16)ls1; vh1[3]=(_Float16)ls2;
            vh1[4]=(_Float16)lc0; vh1[5]=(_Float16)lc1; vh1[6]=(_Float16)lc2;
            DBL();  // l2
            vh1[7]=(_Float16)ls0;
        } else if (f == 1) {
            DBL(); DBL();  // l2
            vh0[0]=(_Float16)ls1; vh0[1]=(_Float16)ls2;
            vh0[2]=(_Float16)lc0; vh0[3]=(_Float16)lc1; vh0[4]=(_Float16)lc2;
            DBL();  // l3
            vh0[5]=(_Float16)ls0; vh0[6]=(_Float16)ls1; vh0[7]=(_Float16)ls2;
            vh1[0]=(_Float16)lc0; vh1[1]=(_Float16)lc1; vh1[2]=(_Float16)lc2;
            DBL();  // l4
            vh1[3]=(_Float16)ls0; vh1[4]=(_Float16)ls1; vh1[5]=(_Float16)ls2;
            vh1[6]=(_Float16)lc0; vh1[7]=(_Float16)lc1;
        } else if (f == 2) {
            DBL(); DBL(); DBL(); DBL();  // l4
            vh0[0]=(_Float16)lc2;
            DBL();  // l5
            vh0[1]=(_Float16)ls0; vh0[2]=(_Float16)ls1; vh0[3]=(_Float16)ls2;
            vh0[4]=(_Float16)lc0; vh0[5]=(_Float16)lc1; vh0[6]=(_Float16)lc2;
            DBL();  // l6
            vh0[7]=(_Float16)ls0; vh1[0]=(_Float16)ls1; vh1[1]=(_Float16)ls2;
            vh1[2]=(_Float16)lc0; vh1[3]=(_Float16)lc1; vh1[4]=(_Float16)lc2;
            DBL();  // l7
            vh1[5]=(_Float16)ls0; vh1[6]=(_Float16)ls1; vh1[7]=(_Float16)ls2;
        } else {
            DBL(); DBL(); DBL(); DBL(); DBL(); DBL(); DBL();  // l7
            vh0[0]=(_Float16)lc0; vh0[1]=(_Float16)lc1; vh0[2]=(_Float16)lc2;
            DBL();  // l8
            vh0[3]=(_Float16)ls0; vh0[4]=(_Float16)ls1; vh0[5]=(_Float16)ls2;
            vh0[6]=(_Float16)lc0; vh0[7]=(_Float16)lc1; vh1[0]=(_Float16)lc2;
            DBL();  // l9
            vh1[1]=(_Float16)ls0; vh1[2]=(_Float16)ls1; vh1[3]=(_Float16)ls2;
            vh1[4]=(_Float16)lc0; vh1[5]=(_Float16)lc1; vh1[6]=(_Float16)lc2;
            vh1[7]=(_Float16)0.0f;
        }
#undef DBL
        ((h8*)B)[(kg*8 + st)*64 + (q0    )*16 + jl] = vh0;
        ((h8*)B)[(kg*8 + st)*64 + (q0 + 1)*16 + jl] = vh1;
    }
    __syncthreads();

    dense_layer<2>(ws+OFF_W0, b0, B, wv, lane, wca, &w1p[fi0], &w1p[fi1]);
    dense_layer<8>(ws+OFF_W1, b1, B, wv, lane, wca, &w2p[fi0], &w2p[fi1]);
    dense_layer<8>(ws+OFF_W2, b2, B, wv, lane, wca,
                   &w3p[wv*64 + lane], &w3p[wv*64 + lane]);

    // ---- head: D[16pad ch][128 samp], K split across 8 waves (kg = wv)
    f4 hacc[8];
    {
        h8 ah = wca[0];                     // W3 frag via the prefetch chain
        const h8* bp = (const h8*)B;
#pragma unroll
        for (int st = 0; st < 8; ++st) {
            f4 z = (f4){0.f, 0.f, 0.f, 0.f};
            hacc[st] = __builtin_amdgcn_mfma_f32_16x16x32_f16(ah, bp[(wv*8 + st)*64 + lane], z, 0, 0, 0);
        }
    }
    __syncthreads();                       // B reads done -> safe to alias

    f4* part = (f4*)sm;                    // [wv][st8][lane] f4 = 64 KB (B region)
#pragma unroll
    for (int st = 0; st < 8; ++st) part[(wv*8 + st)*64 + lane] = hacc[st];
    __syncthreads();

    {
        int stt = tid >> 6, l = tid & 63;
        f4 s = part[(0*8 + stt)*64 + l];
#pragma unroll
        for (int w = 1; w < 8; ++w) s += part[(w*8 + stt)*64 + l];
        int q = l >> 4, jl = l & 15;
        if (q == 0) {                      // rows 0..3 = the real 4 channels
            s += *(const f4*)b3;
            ((f4*)headv)[(stt >> 2)*64 + (stt & 3)*16 + jl] = s;  // [ray][sample]
        }
    }
    __syncthreads();

    // ---- compositing: waves 0-1, lane = sample, wave = ray
    if (tid < 128) {
        const int rr = tid >> 6;
        const int p  = tid & 63;
        f4 f = ((const f4*)headv)[rr*64 + p];
        float sigma = fmaxf(f[3], 0.0f);
        float delta = (near + (float)(p + 1)*step) - (near + (float)p*step);
        float alpha = 1.0f - expf(-sigma * delta);
        float om    = 1.0f - alpha;

        float prod = om;
#pragma unroll
        for (int off = 1; off < 64; off <<= 1) {
            float v = __shfl_up(prod, off, 64);
            if (p >= off) prod *= v;
        }
        float T = __shfl_up(prod, 1, 64);
        if (p == 0) T = 1.0f;
        float w = T * alpha;

        float r  = w * (1.0f / (1.0f + expf(-f[0])));
        float g  = w * (1.0f / (1.0f + expf(-f[1])));
        float bb = w * (1.0f / (1.0f + expf(-f[2])));
#pragma unroll
        for (int off = 32; off > 0; off >>= 1) {
            r  += __shfl_down(r,  off, 64);
            g  += __shfl_down(g,  off, 64);
            bb += __shfl_down(bb, off, 64);
        }
        if (p == 0 && ray0 + rr < nrays) {
            out[(ray0 + rr)*3 + 0] = r;
            out[(ray0 + rr)*3 + 1] = g;
            out[(ray0 + rr)*3 + 2] = bb;
        }
    }
}

extern "C" void kernel_launch(void* const* d_in, const int* in_sizes, int n_in,
                              void* d_out, int out_size, void* d_ws, size_t ws_size,
                              hipStream_t stream) {
    const float* origins = (const float*)d_in[0];
    const float* dirs    = (const float*)d_in[1];
    const float* nearp   = (const float*)d_in[2];
    const float* farp    = (const float*)d_in[3];
    const float* W0      = (const float*)d_in[4];
    const float* b0      = (const float*)d_in[5];
    const float* W1      = (const float*)d_in[6];
    const float* b1      = (const float*)d_in[7];
    const float* W2      = (const float*)d_in[8];
    const float* b2      = (const float*)d_in[9];
    const float* W3      = (const float*)d_in[10];
    const float* b3      = (const float*)d_in[11];
    float* out           = (float*)d_out;
    _Float16* ws         = (_Float16*)d_ws;

    const int nrays = in_sizes[0] / 3;
    const int nblk  = (nrays + 1) / 2;

    prep_weights<<<dim3(74), dim3(256), 0, stream>>>(W0, W1, W2, W3, ws);

    const size_t shmem = 32768 * sizeof(_Float16) + 128 * sizeof(f4);   // 66 KiB
    hipFuncSetAttribute(reinterpret_cast<const void*>(nerf_fused),
                        hipFuncAttributeMaxDynamicSharedMemorySize,
                        (int)shmem);
    nerf_fused<<<dim3(nblk), dim3(512), shmem, stream>>>(
        origins, dirs, nearp, farp, b0, b1, b2, b3, ws, out, nrays);
}